// Round 14
// baseline (244.877 us; speedup 1.0000x reference)
//
#include <hip/hip_runtime.h>
#include <hip/hip_bf16.h>
#include <stdint.h>

// Attention: b=4, n=4097, d=128, h=8, dh=16, scale = d**-0.5.
// Interface (R5): fp32 in, fp32 out, ws >= 33.6MB usable.
// R14: DIAGNOSTIC ROUND. attn split into 4 dispatches (sp as kernel arg) so
// the top-5 profile can no longer be monopolized by attn replays -- the
// hidden ~25-90us dispatch that has carried the unexplained ~105us residual
// since R6 must show its name+counters. All other kernels byte-frozen (R13).
// Suspects: out_mfma / qkv_mfma (257 blocks = 1 wave/SIMD, latency-naked).

#define BB 4
#define NN 4097
#define NNP 4112
#define DD 128
#define HH 8
#define DH 16
#define BH (BB*HH)    // 32
#define ROWS (BB*NN)  // 16388
#define MT  1025      // ceil(ROWS/16) m-tiles

typedef _Float16 h4 __attribute__((ext_vector_type(4)));
typedef _Float16 h8 __attribute__((ext_vector_type(8)));
typedef __fp16   fp16v2 __attribute__((ext_vector_type(2)));
typedef float    f4 __attribute__((ext_vector_type(4)));

#define QSCALE (0.08838834764831845f * 1.4426950408889634f)  // 128^-.5 * log2e

#if __has_builtin(__builtin_amdgcn_exp2f)
#define EXP2F(x) __builtin_amdgcn_exp2f(x)
#else
#define EXP2F(x) exp2f(x)
#endif

union H4u { h4 v; fp16v2 p[2]; };

static __device__ __forceinline__ H4u pack4u(float a, float b, float c, float d) {
    H4u u;
#if __has_builtin(__builtin_amdgcn_cvt_pkrtz)
    u.p[0] = __builtin_amdgcn_cvt_pkrtz(a, b);
    u.p[1] = __builtin_amdgcn_cvt_pkrtz(c, d);
#else
    u.v[0] = (_Float16)a; u.v[1] = (_Float16)b; u.v[2] = (_Float16)c; u.v[3] = (_Float16)d;
#endif
    return u;
}

// ---------------- K0: prep — x->f16, W_qkv^T (Q-scaled) + W_out^T in f16 -------
__global__ __launch_bounds__(256) void prep(
    const float* __restrict__ x,
    const float* __restrict__ Wqkv,
    const float* __restrict__ Wout,
    _Float16* __restrict__ x16,     // [ROWS][128]
    _Float16* __restrict__ WqkvT,   // [384][128], rows 0..127 pre-scaled by QSCALE
    _Float16* __restrict__ WoutT)   // [128][128]
{
    const int id = blockIdx.x*256 + threadIdx.x;
    const int NX8 = ROWS*DD/8;                  // 262208
    if (id < NX8) {
        const float4* s = (const float4*)(x + (size_t)id*8);
        const float4 a = s[0], b = s[1];
        const H4u u0 = pack4u(a.x, a.y, a.z, a.w);
        const H4u u1 = pack4u(b.x, b.y, b.z, b.w);
        h4* d = (h4*)(x16 + (size_t)id*8);
        d[0] = u0.v; d[1] = u1.v;
    } else if (id < NX8 + 384*128) {
        const int e = id - NX8;
        const int n = e >> 7, k = e & 127;
        const float s = (n < 128) ? QSCALE : 1.0f;
        WqkvT[e] = (_Float16)(Wqkv[k*384 + n] * s);
    } else if (id < NX8 + 384*128 + 128*128) {
        const int e = id - NX8 - 384*128;
        const int n = e >> 7, k = e & 127;
        WoutT[e] = (_Float16)(Wout[k*128 + n]);
    }
}

// ---------------- K1: qkv = x16 @ WqkvT^T + b, via MFMA (R13-frozen) -----------
__global__ __launch_bounds__(256) void qkv_mfma(
    const _Float16* __restrict__ x16,
    const _Float16* __restrict__ WqkvT,
    const float* __restrict__ bqkv,
    _Float16* __restrict__ Qh,    // [BH][NNP][16]
    _Float16* __restrict__ Kh,    // [BH][NNP][16]
    _Float16* __restrict__ Vh)    // [BH][NNP][16] row-major
{
    const int wid  = blockIdx.x*4 + (threadIdx.x >> 6);   // m-tile
    if (wid >= MT) return;
    const int lane = threadIdx.x & 63;
    const int quad = lane >> 4, l16 = lane & 15;

    const int arow = wid*16 + l16;
    const int arc  = (arow < ROWS) ? arow : (ROWS - 1);
    h4 af[8];
    #pragma unroll
    for (int kk = 0; kk < 8; ++kk)
        af[kk] = *(const h4*)(x16 + (size_t)arc*DD + kk*16 + quad*4);

    const int r0 = wid*16 + quad*4;

    for (int nt = 0; nt < 24; nt += 2) {
        const float b0 = bqkv[nt*16 + l16]      * ((nt   < 8) ? QSCALE : 1.0f);
        const float b1 = bqkv[nt*16 + 16 + l16] * ((nt+1 < 8) ? QSCALE : 1.0f);
        f4 a0 = {b0,b0,b0,b0}, a1 = {b1,b1,b1,b1};
        #pragma unroll
        for (int kk = 0; kk < 8; ++kk) {
            const h4 bf0 = *(const h4*)(WqkvT + (size_t)(nt*16     + l16)*DD + kk*16 + quad*4);
            const h4 bf1 = *(const h4*)(WqkvT + (size_t)(nt*16 + 16 + l16)*DD + kk*16 + quad*4);
            a0 = __builtin_amdgcn_mfma_f32_16x16x16f16(af[kk], bf0, a0, 0, 0, 0);
            a1 = __builtin_amdgcn_mfma_f32_16x16x16f16(af[kk], bf1, a1, 0, 0, 0);
        }
        #pragma unroll
        for (int u = 0; u < 2; ++u) {
            const int ntc = nt + u;
            const int which = ntc >> 3, head = ntc & 7;
            _Float16* base = (which == 0) ? Qh : ((which == 1) ? Kh : Vh);
            const f4 av = u ? a1 : a0;
            #pragma unroll
            for (int r = 0; r < 4; ++r) {
                const int row = r0 + r;
                if (row < ROWS) {
                    const int bidx = row / NN;
                    const int nrow = row - bidx*NN;
                    base[((size_t)(bidx*HH + head)*NNP + nrow)*DH + l16] = (_Float16)av[r];
                }
            }
        }
    }
}

// ---------------- K1b: Vh [bh][n][16] -> Vt [bh][16][NNP] (R10-frozen) ---------
__global__ __launch_bounds__(256) void vt_transpose(
    const _Float16* __restrict__ Vh,
    _Float16* __restrict__ Vt)
{
    __shared__ _Float16 tile[128][DH + 2];
    const int tl  = blockIdx.x;              // 0..32
    const int bh  = blockIdx.y;              // 0..31
    const int tid = threadIdx.x;             // 0..255
    const int n0  = tl * 128;
    const int rem = (n0 + 128 <= NNP) ? 128 : (NNP - n0);

    {
        const int r  = tid >> 1;
        const int i8 = (tid & 1) * 8;
        const int rc = (r < rem) ? r : (rem - 1);
        const h8 v = *(const h8*)(Vh + ((size_t)bh*NNP + n0 + rc)*DH + i8);
        #pragma unroll
        for (int j = 0; j < 8; ++j) tile[r][i8 + j] = v[j];
    }
    __syncthreads();
    {
        const int i    = tid >> 4;      // 0..15
        const int nseg = tid & 15;      // 0..15
        if (nseg * 8 < rem) {
            h8 v;
            #pragma unroll
            for (int j = 0; j < 8; ++j) v[j] = tile[nseg*8 + j][i];
            *(h8*)(Vt + ((size_t)bh*DH + i)*NNP + n0 + nseg*8) = v;
        }
    }
}

// ---------------- K2: MFMA flash attention (R11-frozen, sp now an arg) ---------
__global__ __launch_bounds__(256, 8) void attn_mfma(
    const _Float16* __restrict__ Qh,
    const _Float16* __restrict__ Kh,
    const _Float16* __restrict__ Vt,
    _Float16* __restrict__ PACC,   // [4][ROWS][DD] per-split normalized out (f16)
    float* __restrict__ PL,        // [4][ROWS][HH] per-split row sums
    const int sp)                  // key split 0..3 (was blockIdx.z)
{
    const int qt   = blockIdx.x;       // 0..16
    const int bh   = blockIdx.y;       // 0..31
    const int tid  = threadIdx.x;
    const int wave = tid >> 6;
    const int lane = tid & 63;
    const int quad = lane >> 4;
    const int l16  = lane & 15;
    const int bidx = bh >> 3, head = bh & 7;

    const int qbase = qt*256 + wave*64;

    const _Float16* Qb = Qh + (size_t)bh*NNP*DH;
    h4 qf[4];
    #pragma unroll
    for (int g = 0; g < 4; ++g) {
        const int qr = qbase + g*16 + l16;
        const int qc = (qr < NN) ? qr : (NN-1);
        qf[g] = *(const h4*)(Qb + (size_t)qc*DH + quad*4);
    }

    f4 acc[4] = {{0,0,0,0},{0,0,0,0},{0,0,0,0},{0,0,0,0}};
    float ls[4] = {0.f,0.f,0.f,0.f};

    const int t0 = sp*64;
    const int t1 = t0 + 64;

    const _Float16* kp = Kh + ((size_t)bh*NNP + (size_t)t0*16 + l16)*DH + quad*4;
    const _Float16* vp = Vt + ((size_t)bh*DH + l16)*NNP + t0*16 + quad*4;

    h4 ak = *(const h4*)kp;
    h4 av = *(const h4*)vp;
    const f4 zero = {0.f,0.f,0.f,0.f};
#if __has_builtin(__builtin_amdgcn_fdot2)
    const fp16v2 one2 = {(__fp16)1.0f, (__fp16)1.0f};
#endif

    for (int tt = t0; tt < t1; ++tt) {
        kp += 16*DH; vp += 16;
        const h4 nak = *(const h4*)kp;   // prefetch (tile <= 256 in-bounds)
        const h4 nav = *(const h4*)vp;
        #pragma unroll
        for (int g = 0; g < 4; ++g) {
            f4 d = __builtin_amdgcn_mfma_f32_16x16x16f16(ak, qf[g], zero, 0, 0, 0);
            const float p0 = EXP2F(d[0]), p1 = EXP2F(d[1]), p2 = EXP2F(d[2]), p3 = EXP2F(d[3]);
            const H4u pb = pack4u(p0, p1, p2, p3);
#if __has_builtin(__builtin_amdgcn_fdot2)
            ls[g] = __builtin_amdgcn_fdot2(pb.p[0], one2,
                     __builtin_amdgcn_fdot2(pb.p[1], one2, ls[g], false), false);
#else
            ls[g] += (p0 + p1) + (p2 + p3);
#endif
            acc[g] = __builtin_amdgcn_mfma_f32_16x16x16f16(av, pb.v, acc[g], 0, 0, 0);
        }
        ak = nak; av = nav;
    }

    if (sp == 3) {   // tile 256: keys 4096..4111; only key 4096 (quad==0, reg 0) valid
        #pragma unroll
        for (int g = 0; g < 4; ++g) {
            f4 d = __builtin_amdgcn_mfma_f32_16x16x16f16(ak, qf[g], zero, 0, 0, 0);
            const float p0 = (quad == 0) ? EXP2F(d[0]) : 0.f;
            ls[g] += p0;
            const H4u pb = pack4u(p0, 0.f, 0.f, 0.f);
            acc[g] = __builtin_amdgcn_mfma_f32_16x16x16f16(av, pb.v, acc[g], 0, 0, 0);
        }
    }

    const size_t rb = (size_t)sp*ROWS + (size_t)bidx*NN;
    #pragma unroll
    for (int g = 0; g < 4; ++g) {
        float l = ls[g];
        l += __shfl_xor(l, 16);
        l += __shfl_xor(l, 32);
        const int qr = qbase + g*16 + l16;
        if (qr < NN) {
            const float inv = 1.0f / l;   // per-split normalize: f16-safe range
            const H4u st = pack4u(acc[g][0]*inv, acc[g][1]*inv, acc[g][2]*inv, acc[g][3]*inv);
            *(h4*)(PACC + (rb + qr)*DD + head*DH + quad*4) = st.v;
            if (quad == 0) PL[(rb + qr)*HH + head] = l;
        }
    }
}

// ---------------- K3: merged-AO @ Wout + b via MFMA (R13-frozen) ----------------
__global__ __launch_bounds__(256) void out_mfma(
    const _Float16* __restrict__ PACC,
    const float* __restrict__ PL,
    const _Float16* __restrict__ WoutT,   // [128][128]
    const float* __restrict__ bout,
    float* __restrict__ out)
{
    const int wid  = blockIdx.x*4 + (threadIdx.x >> 6);   // m-tile
    if (wid >= MT) return;
    const int lane = threadIdx.x & 63;
    const int quad = lane >> 4, l16 = lane & 15;

    const int arow = wid*16 + l16;
    const int arc  = (arow < ROWS) ? arow : (ROWS - 1);

    h4 af[8];
    #pragma unroll
    for (int kk = 0; kk < 8; ++kk) {
        float n0 = 0.f, n1 = 0.f, n2 = 0.f, n3 = 0.f, lsum = 0.f;
        #pragma unroll
        for (int sp = 0; sp < 4; ++sp) {
            const float l = PL[((size_t)sp*ROWS + arc)*HH + kk];   // head == kk
            lsum += l;
            const h4 p = *(const h4*)(PACC + ((size_t)sp*ROWS + arc)*DD + kk*16 + quad*4);
            n0 += l*(float)p[0]; n1 += l*(float)p[1];
            n2 += l*(float)p[2]; n3 += l*(float)p[3];
        }
        const float inv = 1.0f / lsum;
        const H4u u = pack4u(n0*inv, n1*inv, n2*inv, n3*inv);
        af[kk] = u.v;
    }

    const int r0 = wid*16 + quad*4;

    for (int nt = 0; nt < 8; nt += 2) {
        const float b0 = bout[nt*16 + l16];
        const float b1 = bout[nt*16 + 16 + l16];
        f4 a0 = {b0,b0,b0,b0}, a1 = {b1,b1,b1,b1};
        #pragma unroll
        for (int kk = 0; kk < 8; ++kk) {
            const h4 bf0 = *(const h4*)(WoutT + (size_t)(nt*16      + l16)*DD + kk*16 + quad*4);
            const h4 bf1 = *(const h4*)(WoutT + (size_t)(nt*16 + 16 + l16)*DD + kk*16 + quad*4);
            a0 = __builtin_amdgcn_mfma_f32_16x16x16f16(af[kk], bf0, a0, 0, 0, 0);
            a1 = __builtin_amdgcn_mfma_f32_16x16x16f16(af[kk], bf1, a1, 0, 0, 0);
        }
        #pragma unroll
        for (int r = 0; r < 4; ++r) {
            const int row = r0 + r;
            if (row < ROWS) {
                out[(size_t)row*DD + nt*16      + l16] = a0[r];
                out[(size_t)row*DD + nt*16 + 16 + l16] = a1[r];
            }
        }
    }
}

extern "C" void kernel_launch(void* const* d_in, const int* in_sizes, int n_in,
                              void* d_out, int out_size, void* d_ws, size_t ws_size,
                              hipStream_t stream) {
    const float* x    = (const float*)d_in[0];
    const float* Wqkv = (const float*)d_in[1];
    const float* bqkv = (const float*)d_in[2];
    const float* Wout = (const float*)d_in[3];
    const float* bout = (const float*)d_in[4];
    for (int i = 0; i < n_in; ++i) {
        switch (in_sizes[i]) {
            case 2097664: x    = (const float*)d_in[i]; break;
            case 49152:   Wqkv = (const float*)d_in[i]; break;
            case 384:     bqkv = (const float*)d_in[i]; break;
            case 16384:   Wout = (const float*)d_in[i]; break;
            case 128:     bout = (const float*)d_in[i]; break;
            default: break;
        }
    }
    float* out = (float*)d_out;

    const size_t perh = (size_t)BH * NNP * DH;            // 2,105,344 f16
    _Float16* Qh   = (_Float16*)d_ws;                     // 4.21 MB
    _Float16* Kh   = Qh + perh;                           // 4.21 MB
    _Float16* Vt   = Kh + perh;                           // 4.21 MB
    _Float16* Vh   = Vt + perh;                           // 4.21 MB (dead after vt)
    _Float16* PACC = Vh;                                  // [4][ROWS][DD] f16 16.78 MB
    _Float16* x16  = Vh + perh;                           // 4.2 MB, inside PACC tail
    float*    PL    = (float*)(PACC + (size_t)4*ROWS*DD); // 2.1 MB
    _Float16* WqkvT = (_Float16*)(PL + (size_t)4*ROWS*HH);// 96 KB
    _Float16* WoutT = WqkvT + 384*128;                    // 32 KB -> total ~31.7 MB

    const int NX8 = ROWS*DD/8;
    const int prep_total = NX8 + 384*128 + 128*128;

    hipLaunchKernelGGL(prep, dim3((prep_total + 255)/256), dim3(256), 0, stream,
                       x, Wqkv, Wout, x16, WqkvT, WoutT);
    hipLaunchKernelGGL(qkv_mfma, dim3((MT + 3)/4), dim3(256), 0, stream,
                       x16, WqkvT, bqkv, Qh, Kh, Vh);
    hipLaunchKernelGGL(vt_transpose, dim3(33, BH), dim3(256), 0, stream,
                       Vh, Vt);
    for (int sp = 0; sp < 4; ++sp)
        hipLaunchKernelGGL(attn_mfma, dim3(17, BH), dim3(256), 0, stream,
                           Qh, Kh, Vt, PACC, PL, sp);
    hipLaunchKernelGGL(out_mfma, dim3((MT + 3)/4), dim3(256), 0, stream,
                       PACC, PL, WoutT, bout, out);
}

// Round 15
// 196.406 us; speedup vs baseline: 1.2468x; 1.2468x over previous
//
#include <hip/hip_runtime.h>
#include <hip/hip_bf16.h>
#include <stdint.h>

// Attention: b=4, n=4097, d=128, h=8, dh=16, scale = d**-0.5.
// Interface (R5): fp32 in, fp32 out; ws = 256MB (R14: fillBuffer 262144KB).
// R15: pipeline collapsed 5 -> 3 kernels. qkv_mfma reads x/Wqkv fp32 directly
// (prep deleted), stages D-tiles in LDS, stores Q/K coalesced 16B and V
// pre-transposed into Vt (vt_transpose deleted). qkv/out n-split x2 grids
// (2 waves/SIMD vs R13's latency-naked 1). attn single-dispatch (R13 exact;
// R14 proved splitting costs ~50us of occupancy).

#define BB 4
#define NN 4097
#define NNP 4112
#define DD 128
#define HH 8
#define DH 16
#define BH (BB*HH)    // 32
#define ROWS (BB*NN)  // 16388
#define MT  1025      // ceil(ROWS/16) m-tiles

typedef _Float16 h4 __attribute__((ext_vector_type(4)));
typedef _Float16 h8 __attribute__((ext_vector_type(8)));
typedef __fp16   fp16v2 __attribute__((ext_vector_type(2)));
typedef float    f4 __attribute__((ext_vector_type(4)));

#define QSCALE (0.08838834764831845f * 1.4426950408889634f)  // 128^-.5 * log2e

#if __has_builtin(__builtin_amdgcn_exp2f)
#define EXP2F(x) __builtin_amdgcn_exp2f(x)
#else
#define EXP2F(x) exp2f(x)
#endif

union H4u { h4 v; fp16v2 p[2]; };

static __device__ __forceinline__ H4u pack4u(float a, float b, float c, float d) {
    H4u u;
#if __has_builtin(__builtin_amdgcn_cvt_pkrtz)
    u.p[0] = __builtin_amdgcn_cvt_pkrtz(a, b);
    u.p[1] = __builtin_amdgcn_cvt_pkrtz(c, d);
#else
    u.v[0] = (_Float16)a; u.v[1] = (_Float16)b; u.v[2] = (_Float16)c; u.v[3] = (_Float16)d;
#endif
    return u;
}

// ---------------- K1: fused qkv projection (MFMA, direct fp32 reads) -----------
// grid (257, 2): blockIdx.y = n-half (12 of 24 col-tiles). 4 m-tiles/block.
// Epilogue: LDS-staged; Q/K as 16B coalesced stores, V transposed into Vt.
__global__ __launch_bounds__(256) void qkv_mfma(
    const float* __restrict__ x,
    const float* __restrict__ Wqkv,
    const float* __restrict__ bqkv,
    _Float16* __restrict__ Qh,    // [BH][NNP][16], scale*log2e folded
    _Float16* __restrict__ Kh,    // [BH][NNP][16]
    _Float16* __restrict__ Vt)    // [BH][16][NNP]
{
    __shared__ _Float16 lds[4][12][16][24];   // stride 24 f16: 16B-aligned rows

    const int tid  = threadIdx.x;
    const int w    = tid >> 6;
    const int lane = tid & 63;
    const int quad = lane >> 4, l16 = lane & 15;
    const int nsel = blockIdx.y;              // 0: nt 0..11, 1: nt 12..23
    const int wid  = blockIdx.x*4 + w;
    const int widc = (wid < MT) ? wid : (MT-1);
    const int arow = widc*16 + l16;
    const int arc  = (arow < ROWS) ? arow : (ROWS-1);

    // A-frags: A[m=l16][k=kk*16+quad*4+j] from x fp32
    h4 af[8];
    #pragma unroll
    for (int kk = 0; kk < 8; ++kk) {
        const float4 xv = *(const float4*)(x + (size_t)arc*DD + kk*16 + quad*4);
        af[kk] = pack4u(xv.x, xv.y, xv.z, xv.w).v;
    }

    f4 acc[12];
    #pragma unroll
    for (int ntl = 0; ntl < 12; ++ntl) {
        const int ntc = nsel*12 + ntl;
        const float b = bqkv[ntc*16 + l16] * ((ntc < 8) ? QSCALE : 1.0f);
        acc[ntl] = (f4){b, b, b, b};
    }

    // B-frags on the fly: B[k][n] = Wqkv[k*384 + n] (stride-384 reads, L2-hot)
    #pragma unroll
    for (int kk = 0; kk < 8; ++kk) {
        const int kb = kk*16 + quad*4;
        const float* Wr = Wqkv + (size_t)kb*384 + nsel*192 + l16;
        #pragma unroll
        for (int ntl = 0; ntl < 12; ++ntl) {
            const float w0 = Wr[ntl*16];
            const float w1 = Wr[384  + ntl*16];
            const float w2 = Wr[768  + ntl*16];
            const float w3 = Wr[1152 + ntl*16];
            const float sc = ((nsel*12 + ntl) < 8) ? QSCALE : 1.0f;
            acc[ntl] = __builtin_amdgcn_mfma_f32_16x16x16f16(
                af[kk], pack4u(w0*sc, w1*sc, w2*sc, w3*sc).v, acc[ntl], 0, 0, 0);
        }
    }

    // stage D tiles: lds[w][ntl][row=quad*4+r][col=l16]
    #pragma unroll
    for (int ntl = 0; ntl < 12; ++ntl) {
        #pragma unroll
        for (int r = 0; r < 4; ++r)
            lds[w][ntl][quad*4 + r][l16] = (_Float16)acc[ntl][r];
    }
    __syncthreads();

    // Q/K tiles -> 16B stores (row j>>1 of m-tile, col-half j&1)
    const int ntqk = (nsel == 0) ? 12 : 4;    // nsel=1: ntl 0..3 are K heads 4..7
    for (int u = tid; u < 4*ntqk*32; u += 256) {
        const int w2  = u / (ntqk*32);
        const int rem = u - w2*(ntqk*32);
        const int ntl = rem >> 5;
        const int j   = rem & 31;
        const int ntc = nsel*12 + ntl;
        const int head = ntc & 7;
        const int row = (blockIdx.x*4 + w2)*16 + (j >> 1);
        if (row >= ROWS) continue;
        const int bidx = row / NN;
        const int nrow = row - bidx*NN;
        _Float16* base = ((ntc >> 3) == 0) ? Qh : Kh;
        const h8 v = *(const h8*)&lds[w2][ntl][j >> 1][(j & 1)*8];
        *(h8*)(base + ((size_t)(bidx*HH + head)*NNP + nrow)*DH + (j & 1)*8) = v;
    }

    // V tiles (nsel==1, ntl 4..11) -> transposed into Vt (contiguous-n runs)
    if (nsel == 1) {
        for (int u = tid; u < 512; u += 256) {
            const int w2   = u >> 7;
            const int rem  = u & 127;
            const int ntl  = 4 + (rem >> 4);
            const int c    = rem & 15;          // dh index
            const int head = ntl - 4;
            const int row0 = (blockIdx.x*4 + w2)*16;
            #pragma unroll
            for (int rr = 0; rr < 16; ++rr) {
                const int row = row0 + rr;
                if (row >= ROWS) break;
                const int bidx = row / NN;
                const int nrow = row - bidx*NN;
                Vt[((size_t)(bidx*HH + head)*DH + c)*NNP + nrow] = lds[w2][ntl][rr][c];
            }
        }
    }
}

// ---------------- K2: MFMA flash attention (R13 exact) ----------------
__global__ __launch_bounds__(256, 8) void attn_mfma(
    const _Float16* __restrict__ Qh,
    const _Float16* __restrict__ Kh,
    const _Float16* __restrict__ Vt,
    _Float16* __restrict__ PACC,   // [4][ROWS][DD] per-split normalized out (f16)
    float* __restrict__ PL)        // [4][ROWS][HH] per-split row sums
{
    const int qt   = blockIdx.x;       // 0..16
    const int bh   = blockIdx.y;       // 0..31
    const int sp   = blockIdx.z;       // 0..3
    const int tid  = threadIdx.x;
    const int wave = tid >> 6;
    const int lane = tid & 63;
    const int quad = lane >> 4;
    const int l16  = lane & 15;
    const int bidx = bh >> 3, head = bh & 7;

    const int qbase = qt*256 + wave*64;

    const _Float16* Qb = Qh + (size_t)bh*NNP*DH;
    h4 qf[4];
    #pragma unroll
    for (int g = 0; g < 4; ++g) {
        const int qr = qbase + g*16 + l16;
        const int qc = (qr < NN) ? qr : (NN-1);
        qf[g] = *(const h4*)(Qb + (size_t)qc*DH + quad*4);
    }

    f4 acc[4] = {{0,0,0,0},{0,0,0,0},{0,0,0,0},{0,0,0,0}};
    float ls[4] = {0.f,0.f,0.f,0.f};

    const int t0 = sp*64;
    const int t1 = t0 + 64;

    const _Float16* kp = Kh + ((size_t)bh*NNP + (size_t)t0*16 + l16)*DH + quad*4;
    const _Float16* vp = Vt + ((size_t)bh*DH + l16)*NNP + t0*16 + quad*4;

    h4 ak = *(const h4*)kp;
    h4 av = *(const h4*)vp;
    const f4 zero = {0.f,0.f,0.f,0.f};
#if __has_builtin(__builtin_amdgcn_fdot2)
    const fp16v2 one2 = {(__fp16)1.0f, (__fp16)1.0f};
#endif

    for (int tt = t0; tt < t1; ++tt) {
        kp += 16*DH; vp += 16;
        const h4 nak = *(const h4*)kp;   // prefetch (tile <= 256 in-bounds)
        const h4 nav = *(const h4*)vp;
        #pragma unroll
        for (int g = 0; g < 4; ++g) {
            f4 d = __builtin_amdgcn_mfma_f32_16x16x16f16(ak, qf[g], zero, 0, 0, 0);
            const float p0 = EXP2F(d[0]), p1 = EXP2F(d[1]), p2 = EXP2F(d[2]), p3 = EXP2F(d[3]);
            const H4u pb = pack4u(p0, p1, p2, p3);
#if __has_builtin(__builtin_amdgcn_fdot2)
            ls[g] = __builtin_amdgcn_fdot2(pb.p[0], one2,
                     __builtin_amdgcn_fdot2(pb.p[1], one2, ls[g], false), false);
#else
            ls[g] += (p0 + p1) + (p2 + p3);
#endif
            acc[g] = __builtin_amdgcn_mfma_f32_16x16x16f16(av, pb.v, acc[g], 0, 0, 0);
        }
        ak = nak; av = nav;
    }

    if (sp == 3) {   // tile 256: keys 4096..4111; only key 4096 (quad==0, reg 0) valid
        #pragma unroll
        for (int g = 0; g < 4; ++g) {
            f4 d = __builtin_amdgcn_mfma_f32_16x16x16f16(ak, qf[g], zero, 0, 0, 0);
            const float p0 = (quad == 0) ? EXP2F(d[0]) : 0.f;
            ls[g] += p0;
            const H4u pb = pack4u(p0, 0.f, 0.f, 0.f);
            acc[g] = __builtin_amdgcn_mfma_f32_16x16x16f16(av, pb.v, acc[g], 0, 0, 0);
        }
    }

    const size_t rb = (size_t)sp*ROWS + (size_t)bidx*NN;
    #pragma unroll
    for (int g = 0; g < 4; ++g) {
        float l = ls[g];
        l += __shfl_xor(l, 16);
        l += __shfl_xor(l, 32);
        const int qr = qbase + g*16 + l16;
        if (qr < NN) {
            const float inv = 1.0f / l;   // per-split normalize: f16-safe range
            const H4u st = pack4u(acc[g][0]*inv, acc[g][1]*inv, acc[g][2]*inv, acc[g][3]*inv);
            *(h4*)(PACC + (rb + qr)*DD + head*DH + quad*4) = st.v;
            if (quad == 0) PL[(rb + qr)*HH + head] = l;
        }
    }
}

// ---------------- K3: merged-AO @ Wout + b via MFMA, n-split x2 ----------------
__global__ __launch_bounds__(256) void out_mfma(
    const _Float16* __restrict__ PACC,
    const float* __restrict__ PL,
    const float* __restrict__ Wout,      // fp32 [128][128], transposed on the fly
    const float* __restrict__ bout,
    float* __restrict__ out)
{
    const int wid  = blockIdx.x*4 + (threadIdx.x >> 6);   // m-tile
    if (wid >= MT) return;
    const int lane = threadIdx.x & 63;
    const int quad = lane >> 4, l16 = lane & 15;
    const int nsel = blockIdx.y;                          // 0: nt 0..3, 1: nt 4..7

    const int arow = wid*16 + l16;
    const int arc  = (arow < ROWS) ? arow : (ROWS - 1);

    // A-frags: 4-split merge (head == kk per k-tile -> exact softmax)
    h4 af[8];
    #pragma unroll
    for (int kk = 0; kk < 8; ++kk) {
        float n0 = 0.f, n1 = 0.f, n2 = 0.f, n3 = 0.f, lsum = 0.f;
        #pragma unroll
        for (int sp = 0; sp < 4; ++sp) {
            const float l = PL[((size_t)sp*ROWS + arc)*HH + kk];
            lsum += l;
            const h4 p = *(const h4*)(PACC + ((size_t)sp*ROWS + arc)*DD + kk*16 + quad*4);
            n0 += l*(float)p[0]; n1 += l*(float)p[1];
            n2 += l*(float)p[2]; n3 += l*(float)p[3];
        }
        const float inv = 1.0f / lsum;
        af[kk] = pack4u(n0*inv, n1*inv, n2*inv, n3*inv).v;
    }

    const int r0 = wid*16 + quad*4;

    for (int nt = nsel*4; nt < nsel*4 + 4; nt += 2) {
        const float b0 = bout[nt*16 + l16];
        const float b1 = bout[nt*16 + 16 + l16];
        f4 a0 = {b0,b0,b0,b0}, a1 = {b1,b1,b1,b1};
        #pragma unroll
        for (int kk = 0; kk < 8; ++kk) {
            const int kb = kk*16 + quad*4;
            const float* Wr = Wout + (size_t)kb*DD + nt*16 + l16;
            const h4 bf0 = pack4u(Wr[0],      Wr[DD],      Wr[2*DD],      Wr[3*DD]).v;
            const h4 bf1 = pack4u(Wr[16],     Wr[DD+16],   Wr[2*DD+16],   Wr[3*DD+16]).v;
            a0 = __builtin_amdgcn_mfma_f32_16x16x16f16(af[kk], bf0, a0, 0, 0, 0);
            a1 = __builtin_amdgcn_mfma_f32_16x16x16f16(af[kk], bf1, a1, 0, 0, 0);
        }
        #pragma unroll
        for (int r = 0; r < 4; ++r) {
            const int row = r0 + r;
            if (row < ROWS) {
                out[(size_t)row*DD + nt*16      + l16] = a0[r];   // full-line stores
                out[(size_t)row*DD + nt*16 + 16 + l16] = a1[r];
            }
        }
    }
}

extern "C" void kernel_launch(void* const* d_in, const int* in_sizes, int n_in,
                              void* d_out, int out_size, void* d_ws, size_t ws_size,
                              hipStream_t stream) {
    const float* x    = (const float*)d_in[0];
    const float* Wqkv = (const float*)d_in[1];
    const float* bqkv = (const float*)d_in[2];
    const float* Wout = (const float*)d_in[3];
    const float* bout = (const float*)d_in[4];
    for (int i = 0; i < n_in; ++i) {
        switch (in_sizes[i]) {
            case 2097664: x    = (const float*)d_in[i]; break;
            case 49152:   Wqkv = (const float*)d_in[i]; break;
            case 384:     bqkv = (const float*)d_in[i]; break;
            case 16384:   Wout = (const float*)d_in[i]; break;
            case 128:     bout = (const float*)d_in[i]; break;
            default: break;
        }
    }
    float* out = (float*)d_out;

    const size_t perh = (size_t)BH * NNP * DH;            // 2,105,344 f16
    _Float16* Qh   = (_Float16*)d_ws;                     // 4.21 MB
    _Float16* Kh   = Qh + perh;                           // 4.21 MB
    _Float16* Vt   = Kh + perh;                           // 4.21 MB
    _Float16* PACC = Vt + perh;                           // [4][ROWS][DD] f16 16.78 MB
    float*    PL   = (float*)(PACC + (size_t)4*ROWS*DD);  // 2.1 MB -> total 31.5 MB

    hipLaunchKernelGGL(qkv_mfma, dim3((MT + 3)/4, 2), dim3(256), 0, stream,
                       x, Wqkv, bqkv, Qh, Kh, Vt);
    hipLaunchKernelGGL(attn_mfma, dim3(17, BH, 4), dim3(256), 0, stream,
                       Qh, Kh, Vt, PACC, PL);
    hipLaunchKernelGGL(out_mfma, dim3((MT + 3)/4, 2), dim3(256), 0, stream,
                       PACC, PL, Wout, bout, out);
}